// Round 1
// baseline (419.982 us; speedup 1.0000x reference)
//
#include <hip/hip_runtime.h>

typedef __bf16 bf16x8 __attribute__((ext_vector_type(8)));
typedef __bf16 bf16x4 __attribute__((ext_vector_type(4)));
typedef float f32x4 __attribute__((ext_vector_type(4)));

__device__ __forceinline__ f32x4 mfma16(bf16x8 a, bf16x8 b, f32x4 c) {
  return __builtin_amdgcn_mfma_f32_16x16x32_bf16(a, b, c, 0, 0, 0);
}

// ---------------- fp32 -> bf16 convert ----------------
__global__ __launch_bounds__(256) void f2b(const float* __restrict__ src,
                                           __bf16* __restrict__ dst, int n) {
  int i = (blockIdx.x * 256 + threadIdx.x) * 4;
  if (i < n) {
    float4 v = *(const float4*)(src + i);
    bf16x4 o = { (__bf16)v.x, (__bf16)v.y, (__bf16)v.z, (__bf16)v.w };
    *(bf16x4*)(dst + i) = o;
  }
}

// ---------------- NT GEMM: C[M,N] = A[M,1024] * B[N,1024]^T ----------------
// 64x64 tile per block, 4 waves, each wave computes 16 rows x 64 cols.
template <bool BF16_OUT>
__global__ __launch_bounds__(256) void gemm_nt(const __bf16* __restrict__ A,
                                               const __bf16* __restrict__ B,
                                               void* __restrict__ Cv, int N) {
  __shared__ __bf16 As[64][32];
  __shared__ __bf16 Bs[64][32];
  const int m0 = blockIdx.x * 64, n0 = blockIdx.y * 64;
  const int tid = threadIdx.x;
  const int wave = tid >> 6, lane = tid & 63, quad = lane >> 4, l16 = lane & 15;
  const int lr = tid >> 2, lc = (tid & 3) * 8;  // 256 threads stage 64x32 bf16 (8 each)
  f32x4 acc[4] = {};
  const __bf16* Ap = A + (size_t)(m0 + lr) * 1024 + lc;
  const __bf16* Bp = B + (size_t)(n0 + lr) * 1024 + lc;
  for (int k0 = 0; k0 < 1024; k0 += 32) {
    __syncthreads();
    *(uint4*)&As[lr][lc] = *(const uint4*)(Ap + k0);
    *(uint4*)&Bs[lr][lc] = *(const uint4*)(Bp + k0);
    __syncthreads();
    bf16x8 af = *(bf16x8*)&As[wave * 16 + l16][quad * 8];
#pragma unroll
    for (int t = 0; t < 4; t++) {
      bf16x8 bf = *(bf16x8*)&Bs[t * 16 + l16][quad * 8];
      acc[t] = mfma16(af, bf, acc[t]);
    }
  }
#pragma unroll
  for (int t = 0; t < 4; t++) {
#pragma unroll
    for (int r = 0; r < 4; r++) {
      int row = m0 + wave * 16 + quad * 4 + r;
      int col = n0 + t * 16 + l16;
      if constexpr (BF16_OUT)
        ((__bf16*)Cv)[(size_t)row * N + col] = (__bf16)acc[t][r];
      else
        ((float*)Cv)[(size_t)row * N + col] = acc[t][r];
    }
  }
}

// ---------------- RoPE in-place on bf16 Q [4096,1024] and K [4096,256] ------
__global__ __launch_bounds__(256) void rope(__bf16* __restrict__ Qb,
                                            __bf16* __restrict__ Kb) {
  int idx = blockIdx.x * 256 + threadIdx.x;
  const int nq = 4096 * 32 * 16;  // tokens * qheads * pairs
  __bf16* base;
  int m, i;
  if (idx < nq) {
    m = idx >> 9;              // 32 heads * 16 pairs
    int h = (idx >> 4) & 31;
    i = idx & 15;
    base = Qb + (size_t)m * 1024 + h * 32;
  } else {
    int j = idx - nq;          // 4096 * 8 * 16 total
    m = j >> 7;
    int h = (j >> 4) & 7;
    i = j & 15;
    base = Kb + (size_t)m * 256 + h * 32;
  }
  int s = m & 2047;
  // inv_freq[i] = 10000^(-i/16) = exp(-i * ln(10000)/16)
  float inv = __expf(-(float)i * 0.5756462732485114f);
  float ang = (float)s * inv;
  float sn, cs;
  __sincosf(ang, &sn, &cs);
  float x0 = (float)base[i];
  float x1 = (float)base[i + 16];
  base[i] = (__bf16)(x0 * cs - x1 * sn);
  base[i + 16] = (__bf16)(x1 * cs + x0 * sn);
}

// ---------------- V transpose: Vb[b*2048+s][hkv*32+d] -> VT[(b*8+hkv)*32+d][s]
__global__ __launch_bounds__(256) void vtrans(const __bf16* __restrict__ Vb,
                                              __bf16* __restrict__ VT) {
  int idx = blockIdx.x * 256 + threadIdx.x;  // 2*8*32*512 = 262144 threads
  int s4 = idx & 511;
  int d = (idx >> 9) & 31;
  int hb_ = idx >> 14;  // b*8 + hkv, 0..15
  int s = s4 * 4;
  int b_ = hb_ >> 3, hkv_ = hb_ & 7;
  const __bf16* src = Vb + (size_t)(b_ * 2048 + s) * 256 + hkv_ * 32 + d;
  bf16x4 ov = { src[0], src[256], src[512], src[768] };
  *(bf16x4*)&VT[((size_t)hb_ * 32 + d) * 2048 + s] = ov;
}

// ---------------- Flash attention: wave = 16 q rows of one (b,h) ------------
__global__ __launch_bounds__(256) void attn(const __bf16* __restrict__ Qb,
                                            const __bf16* __restrict__ Kb,
                                            const __bf16* __restrict__ VT,
                                            const int* __restrict__ amask,
                                            __bf16* __restrict__ Ob) {
  __shared__ __bf16 Ps[4][16][32];  // per-wave P scratch (C-layout -> A-layout)
  const int wave = threadIdx.x >> 6, lane = threadIdx.x & 63;
  const int quad = lane >> 4, l16 = lane & 15;
  const int b = blockIdx.z, h = blockIdx.y, hkv = h >> 2;
  const int q0 = blockIdx.x * 64 + wave * 16;
  const float sc = 0.17677669529663687f;  // 1/sqrt(32)

  // Q fragment (A-layout): lane holds Q[q0 + l16][d = quad*8 .. +8]
  const __bf16* qptr = Qb + (size_t)(b * 2048 + q0 + l16) * 1024 + h * 32 + quad * 8;
  bf16x8 qf = *(const bf16x8*)qptr;

  f32x4 o0 = {}, o1 = {};
  float m_r[4], l_r[4];
#pragma unroll
  for (int r = 0; r < 4; r++) { m_r[r] = -INFINITY; l_r[r] = 0.f; }

  const int ntiles = (q0 + 16 + 31) >> 5;
  for (int t = 0; t < ntiles; t++) {
    const int kv0 = t << 5;
    // K fragments (B-layout): lane holds K[kv][d = quad*8 .. +8]
    const __bf16* kbase = Kb + (size_t)(b * 2048 + kv0) * 256 + hkv * 32 + quad * 8;
    bf16x8 kf0 = *(const bf16x8*)(kbase + (size_t)l16 * 256);
    bf16x8 kf1 = *(const bf16x8*)(kbase + (size_t)(16 + l16) * 256);
    f32x4 z = {};
    f32x4 s0 = mfma16(qf, kf0, z);  // rows q0+quad*4+r, col kv0+l16
    f32x4 s1 = mfma16(qf, kf1, z);  // col kv0+16+l16

    const int kvA = kv0 + l16, kvB = kv0 + 16 + l16;
    const bool mA = amask[b * 2048 + kvA] != 0;
    const bool mB = amask[b * 2048 + kvB] != 0;
    float p0[4], p1[4];
#pragma unroll
    for (int r = 0; r < 4; r++) {
      int qg = q0 + quad * 4 + r;
      float v0 = (mA && kvA <= qg) ? s0[r] * sc : -1e9f;
      float v1 = (mB && kvB <= qg) ? s1[r] * sc : -1e9f;
      float mx = fmaxf(v0, v1);
      mx = fmaxf(mx, __shfl_xor(mx, 1));
      mx = fmaxf(mx, __shfl_xor(mx, 2));
      mx = fmaxf(mx, __shfl_xor(mx, 4));
      mx = fmaxf(mx, __shfl_xor(mx, 8));
      float mn = fmaxf(m_r[r], mx);
      float a = __expf(m_r[r] - mn);
      m_r[r] = mn;
      p0[r] = __expf(v0 - mn);
      p1[r] = __expf(v1 - mn);
      float rs = p0[r] + p1[r];
      rs += __shfl_xor(rs, 1);
      rs += __shfl_xor(rs, 2);
      rs += __shfl_xor(rs, 4);
      rs += __shfl_xor(rs, 8);
      l_r[r] = l_r[r] * a + rs;
      o0[r] *= a;
      o1[r] *= a;
    }
    // P: C-layout -> LDS -> A-layout
#pragma unroll
    for (int r = 0; r < 4; r++) {
      Ps[wave][quad * 4 + r][l16] = (__bf16)p0[r];
      Ps[wave][quad * 4 + r][16 + l16] = (__bf16)p1[r];
    }
    asm volatile("s_waitcnt lgkmcnt(0)" ::: "memory");
    bf16x8 pf = *(bf16x8*)&Ps[wave][l16][quad * 8];
    asm volatile("s_waitcnt lgkmcnt(0)" ::: "memory");
    // V fragments (B-layout via VT): lane holds V[kv = kv0+quad*8..+8][d]
    const __bf16* vbase = VT + (size_t)(b * 8 + hkv) * 32 * 2048 + kv0 + quad * 8;
    bf16x8 vf0 = *(const bf16x8*)(vbase + (size_t)l16 * 2048);
    bf16x8 vf1 = *(const bf16x8*)(vbase + (size_t)(16 + l16) * 2048);
    o0 = mfma16(pf, vf0, o0);  // d = l16
    o1 = mfma16(pf, vf1, o1);  // d = 16+l16
  }
  // epilogue: normalize and store bf16 O in [b,s,h,d] layout
#pragma unroll
  for (int r = 0; r < 4; r++) {
    float inv = 1.0f / l_r[r];
    size_t row = (size_t)(b * 2048 + q0 + quad * 4 + r);
    Ob[row * 1024 + h * 32 + l16] = (__bf16)(o0[r] * inv);
    Ob[row * 1024 + h * 32 + 16 + l16] = (__bf16)(o1[r] * inv);
  }
}

extern "C" void kernel_launch(void* const* d_in, const int* in_sizes, int n_in,
                              void* d_out, int out_size, void* d_ws, size_t ws_size,
                              hipStream_t stream) {
  const float* hidden = (const float*)d_in[0];
  const int* amask = (const int*)d_in[1];
  const float* Wq = (const float*)d_in[2];
  const float* Wk = (const float*)d_in[3];
  const float* Wv = (const float*)d_in[4];
  const float* Wo = (const float*)d_in[5];
  float* out = (float*)d_out;

  char* p = (char*)d_ws;
  auto carve = [&](size_t elems) {
    __bf16* r = (__bf16*)p;
    p += ((elems * 2 + 255) / 256) * 256;
    return r;
  };
  __bf16* hb = carve(4096ull * 1024);
  __bf16* Wqb = carve(1024ull * 1024);
  __bf16* Wkb = carve(256ull * 1024);
  __bf16* Wvb = carve(256ull * 1024);
  __bf16* Wob = carve(1024ull * 1024);
  __bf16* Qb = carve(4096ull * 1024);
  __bf16* Kb = carve(4096ull * 256);
  __bf16* Vb = carve(4096ull * 256);
  __bf16* VT = carve(4096ull * 256);
  __bf16* Ob = carve(4096ull * 1024);

  // 1) bf16 conversions
  f2b<<<4096, 256, 0, stream>>>(hidden, hb, 4096 * 1024);
  f2b<<<1024, 256, 0, stream>>>(Wq, Wqb, 1024 * 1024);
  f2b<<<256, 256, 0, stream>>>(Wk, Wkb, 256 * 1024);
  f2b<<<256, 256, 0, stream>>>(Wv, Wvb, 256 * 1024);
  f2b<<<1024, 256, 0, stream>>>(Wo, Wob, 1024 * 1024);

  // 2) QKV projections
  gemm_nt<true><<<dim3(64, 16), 256, 0, stream>>>(hb, Wqb, Qb, 1024);
  gemm_nt<true><<<dim3(64, 4), 256, 0, stream>>>(hb, Wkb, Kb, 256);
  gemm_nt<true><<<dim3(64, 4), 256, 0, stream>>>(hb, Wvb, Vb, 256);

  // 3) RoPE on Q and K
  rope<<<10240, 256, 0, stream>>>(Qb, Kb);

  // 4) V transpose for PV B-fragments
  vtrans<<<1024, 256, 0, stream>>>(Vb, VT);

  // 5) flash attention
  attn<<<dim3(32, 32, 2), 256, 0, stream>>>(Qb, Kb, VT, amask, Ob);

  // 6) output projection (fp32 out)
  gemm_nt<false><<<dim3(64, 16), 256, 0, stream>>>(Ob, Wob, (void*)out, 1024);
}

// Round 2
// 408.609 us; speedup vs baseline: 1.0278x; 1.0278x over previous
//
#include <hip/hip_runtime.h>

typedef __bf16 bf16x8 __attribute__((ext_vector_type(8)));
typedef __bf16 bf16x4 __attribute__((ext_vector_type(4)));
typedef float f32x4 __attribute__((ext_vector_type(4)));

__device__ __forceinline__ f32x4 mfma16(bf16x8 a, bf16x8 b, f32x4 c) {
  return __builtin_amdgcn_mfma_f32_16x16x32_bf16(a, b, c, 0, 0, 0);
}

// ---------------- fp32 -> bf16 convert ----------------
__global__ __launch_bounds__(256) void f2b(const float* __restrict__ src,
                                           __bf16* __restrict__ dst, int n) {
  int i = (blockIdx.x * 256 + threadIdx.x) * 4;
  if (i < n) {
    float4 v = *(const float4*)(src + i);
    bf16x4 o = { (__bf16)v.x, (__bf16)v.y, (__bf16)v.z, (__bf16)v.w };
    *(bf16x4*)(dst + i) = o;
  }
}

// ---------------- NT GEMM: C[M,N] = A[M,1024] * B[N,1024]^T ----------------
// 64x64 tile per block, 4 waves, each wave computes 16 rows x 64 cols.
template <bool BF16_OUT>
__global__ __launch_bounds__(256) void gemm_nt(const __bf16* __restrict__ A,
                                               const __bf16* __restrict__ B,
                                               void* __restrict__ Cv, int N) {
  __shared__ __bf16 As[64][32];
  __shared__ __bf16 Bs[64][32];
  const int m0 = blockIdx.x * 64, n0 = blockIdx.y * 64;
  const int tid = threadIdx.x;
  const int wave = tid >> 6, lane = tid & 63, quad = lane >> 4, l16 = lane & 15;
  const int lr = tid >> 2, lc = (tid & 3) * 8;  // 256 threads stage 64x32 bf16 (8 each)
  f32x4 acc[4] = {};
  const __bf16* Ap = A + (size_t)(m0 + lr) * 1024 + lc;
  const __bf16* Bp = B + (size_t)(n0 + lr) * 1024 + lc;
  for (int k0 = 0; k0 < 1024; k0 += 32) {
    __syncthreads();
    *(uint4*)&As[lr][lc] = *(const uint4*)(Ap + k0);
    *(uint4*)&Bs[lr][lc] = *(const uint4*)(Bp + k0);
    __syncthreads();
    bf16x8 af = *(bf16x8*)&As[wave * 16 + l16][quad * 8];
#pragma unroll
    for (int t = 0; t < 4; t++) {
      bf16x8 bf = *(bf16x8*)&Bs[t * 16 + l16][quad * 8];
      acc[t] = mfma16(af, bf, acc[t]);
    }
  }
#pragma unroll
  for (int t = 0; t < 4; t++) {
#pragma unroll
    for (int r = 0; r < 4; r++) {
      int row = m0 + wave * 16 + quad * 4 + r;
      int col = n0 + t * 16 + l16;
      if constexpr (BF16_OUT)
        ((__bf16*)Cv)[(size_t)row * N + col] = (__bf16)acc[t][r];
      else
        ((float*)Cv)[(size_t)row * N + col] = acc[t][r];
    }
  }
}

// ------- RoPE in-place on QKV [4096,1536]: Q cols 0..1023, K cols 1024..1279
__global__ __launch_bounds__(256) void rope(__bf16* __restrict__ QKV) {
  int idx = blockIdx.x * 256 + threadIdx.x;
  const int nq = 4096 * 32 * 16;  // tokens * qheads * pairs
  __bf16* base;
  int m, i;
  if (idx < nq) {
    m = idx >> 9;              // 32 heads * 16 pairs
    int h = (idx >> 4) & 31;
    i = idx & 15;
    base = QKV + (size_t)m * 1536 + h * 32;
  } else {
    int j = idx - nq;          // 4096 * 8 * 16 total
    m = j >> 7;
    int h = (j >> 4) & 7;
    i = j & 15;
    base = QKV + (size_t)m * 1536 + 1024 + h * 32;
  }
  int s = m & 2047;
  float inv = __expf(-(float)i * 0.5756462732485114f);  // 10000^(-i/16)
  float ang = (float)s * inv;
  float sn, cs;
  __sincosf(ang, &sn, &cs);
  float x0 = (float)base[i];
  float x1 = (float)base[i + 16];
  base[i] = (__bf16)(x0 * cs - x1 * sn);
  base[i + 16] = (__bf16)(x1 * cs + x0 * sn);
}

// ---- V transpose: QKV[b*2048+s][1280+hkv*32+d] -> VT[(b*8+hkv)*32+d][s] ----
__global__ __launch_bounds__(256) void vtrans(const __bf16* __restrict__ QKV,
                                              __bf16* __restrict__ VT) {
  int idx = blockIdx.x * 256 + threadIdx.x;  // 2*8*32*512 = 262144 threads
  int s4 = idx & 511;
  int d = (idx >> 9) & 31;
  int hb_ = idx >> 14;  // b*8 + hkv, 0..15
  int s = s4 * 4;
  int b_ = hb_ >> 3, hkv_ = hb_ & 7;
  const __bf16* src = QKV + (size_t)(b_ * 2048 + s) * 1536 + 1280 + hkv_ * 32 + d;
  bf16x4 ov = { src[0], src[1536], src[3072], src[4608] };
  *(bf16x4*)&VT[((size_t)hb_ * 32 + d) * 2048 + s] = ov;
}

// ---------------- Flash attention, transposed-S formulation ------------------
// wave = 16 q rows of one (b,h); key tile = 64.
// S^T = K*Q^T via MFMA: lane holds S^T[key=kv0+16kt+4*quad+r][q=q0+l16]
//   -> softmax row (fixed q=l16) is 16 regs x 4 quads: local reduce + 2 shfl.
// PV as O^T = V^T * P^T; P^T routed through padded per-wave LDS.
__global__ __launch_bounds__(256) void attn(const __bf16* __restrict__ QKV,
                                            const __bf16* __restrict__ VT,
                                            const int* __restrict__ amask,
                                            __bf16* __restrict__ Ob) {
  __shared__ __bf16 Pl[4][16][68];  // 64 keys + 4 pad (136 B row stride)
  const int wave = threadIdx.x >> 6, lane = threadIdx.x & 63;
  const int quad = lane >> 4, l16 = lane & 15;
  const int b = blockIdx.z, h = blockIdx.y, hkv = h >> 2;
  const int q0 = blockIdx.x * 64 + wave * 16;
  const float sc = 0.17677669529663687f;  // 1/sqrt(32)

  // Q fragment (B operand): lane holds Q[q0+l16][d=quad*8..+8]
  const __bf16* qptr = QKV + (size_t)(b * 2048 + q0 + l16) * 1536 + h * 32 + quad * 8;
  bf16x8 qf = *(const bf16x8*)qptr;

  f32x4 o0 = {}, o1 = {};  // O^T d-tiles 0-15, 16-31 (C-layout)
  float m_r = -INFINITY, l_r = 0.f;
  const int q_row = q0 + l16;
  const int ntiles = (q0 + 16 + 63) >> 6;

  for (int t = 0; t < ntiles; t++) {
    const int kv0 = t << 6;
    // K fragments (A operand): lane holds K[kv0+16kt+l16][d=quad*8..+8]
    const __bf16* kbase =
        QKV + (size_t)(b * 2048 + kv0 + l16) * 1536 + 1024 + hkv * 32 + quad * 8;
    float p[4][4];
    float vmax = -INFINITY;
#pragma unroll
    for (int kt = 0; kt < 4; kt++) {
      bf16x8 kf = *(const bf16x8*)(kbase + (size_t)(16 * kt) * 1536);
      f32x4 z = {};
      f32x4 s = mfma16(kf, qf, z);  // S^T[key=kv0+16kt+4q+r][q=q_row]
      const int kb = kv0 + 16 * kt + 4 * quad;
      int4 am4 = *(const int4*)(amask + b * 2048 + kb);
#pragma unroll
      for (int r = 0; r < 4; r++) {
        int key = kb + r;
        int amr = (&am4.x)[r];
        float v = (amr != 0 && key <= q_row) ? s[r] * sc : -1e9f;
        p[kt][r] = v;
        vmax = fmaxf(vmax, v);
      }
    }
    // full row max: reduce across the 4 quads (lane bits 4,5)
    vmax = fmaxf(vmax, __shfl_xor(vmax, 16));
    vmax = fmaxf(vmax, __shfl_xor(vmax, 32));
    float mn = fmaxf(m_r, vmax);
    float alpha = __expf(m_r - mn);
    m_r = mn;
    float rs = 0.f;
#pragma unroll
    for (int kt = 0; kt < 4; kt++)
#pragma unroll
      for (int r = 0; r < 4; r++) {
        p[kt][r] = __expf(p[kt][r] - mn);
        rs += p[kt][r];
      }
    rs += __shfl_xor(rs, 16);
    rs += __shfl_xor(rs, 32);
    l_r = l_r * alpha + rs;
#pragma unroll
    for (int r = 0; r < 4; r++) { o0[r] *= alpha; o1[r] *= alpha; }
    // P^T -> LDS (keys for q-row l16 at cols 16kt+4quad..+3)
#pragma unroll
    for (int kt = 0; kt < 4; kt++) {
      bf16x4 pk = { (__bf16)p[kt][0], (__bf16)p[kt][1],
                    (__bf16)p[kt][2], (__bf16)p[kt][3] };
      *(bf16x4*)&Pl[wave][l16][16 * kt + 4 * quad] = pk;
    }
    asm volatile("s_waitcnt lgkmcnt(0)" ::: "memory");
    // P^T B-frags: chunk c keys 32c+8*quad..+7 for q-row l16
    bf16x8 pf0 = *(bf16x8*)&Pl[wave][l16][8 * quad];
    bf16x8 pf1 = *(bf16x8*)&Pl[wave][l16][32 + 8 * quad];
    asm volatile("s_waitcnt lgkmcnt(0)" ::: "memory");
    // V^T A-frags: lane holds V^T[d=dt*16+l16][key=kv0+32c+quad*8..+8]
    const __bf16* vbase =
        VT + ((size_t)(b * 8 + hkv) * 32 + l16) * 2048 + kv0 + quad * 8;
    bf16x8 vf00 = *(const bf16x8*)(vbase);
    bf16x8 vf01 = *(const bf16x8*)(vbase + 32);
    bf16x8 vf10 = *(const bf16x8*)(vbase + 16 * 2048);
    bf16x8 vf11 = *(const bf16x8*)(vbase + 16 * 2048 + 32);
    o0 = mfma16(vf00, pf0, o0);
    o0 = mfma16(vf01, pf1, o0);
    o1 = mfma16(vf10, pf0, o1);
    o1 = mfma16(vf11, pf1, o1);
  }
  // epilogue: O^T C-layout -> lane holds O[q_row][d=dt*16+quad*4..+3]
  float inv = 1.0f / l_r;
  size_t row = (size_t)(b * 2048 + q_row);
  bf16x4 w0 = { (__bf16)(o0[0] * inv), (__bf16)(o0[1] * inv),
                (__bf16)(o0[2] * inv), (__bf16)(o0[3] * inv) };
  bf16x4 w1 = { (__bf16)(o1[0] * inv), (__bf16)(o1[1] * inv),
                (__bf16)(o1[2] * inv), (__bf16)(o1[3] * inv) };
  *(bf16x4*)&Ob[row * 1024 + h * 32 + quad * 4] = w0;
  *(bf16x4*)&Ob[row * 1024 + h * 32 + 16 + quad * 4] = w1;
}

extern "C" void kernel_launch(void* const* d_in, const int* in_sizes, int n_in,
                              void* d_out, int out_size, void* d_ws, size_t ws_size,
                              hipStream_t stream) {
  const float* hidden = (const float*)d_in[0];
  const int* amask = (const int*)d_in[1];
  const float* Wq = (const float*)d_in[2];
  const float* Wk = (const float*)d_in[3];
  const float* Wv = (const float*)d_in[4];
  const float* Wo = (const float*)d_in[5];
  float* out = (float*)d_out;

  char* p = (char*)d_ws;
  auto carve = [&](size_t elems) {
    __bf16* r = (__bf16*)p;
    p += ((elems * 2 + 255) / 256) * 256;
    return r;
  };
  __bf16* hb = carve(4096ull * 1024);
  __bf16* Wqkvb = carve(1536ull * 1024);  // rows: 0-1023 Wq, 1024-1279 Wk, 1280-1535 Wv
  __bf16* Wob = carve(1024ull * 1024);
  __bf16* QKV = carve(4096ull * 1536);
  __bf16* VT = carve(4096ull * 256);
  __bf16* Ob = carve(4096ull * 1024);

  // 1) bf16 conversions (QKV weights concatenated)
  f2b<<<4096, 256, 0, stream>>>(hidden, hb, 4096 * 1024);
  f2b<<<1024, 256, 0, stream>>>(Wq, Wqkvb, 1024 * 1024);
  f2b<<<256, 256, 0, stream>>>(Wk, Wqkvb + 1024ull * 1024, 256 * 1024);
  f2b<<<256, 256, 0, stream>>>(Wv, Wqkvb + 1280ull * 1024, 256 * 1024);
  f2b<<<1024, 256, 0, stream>>>(Wo, Wob, 1024 * 1024);

  // 2) fused QKV projection -> QKV [4096][1536]
  gemm_nt<true><<<dim3(64, 24), 256, 0, stream>>>(hb, Wqkvb, QKV, 1536);

  // 3) RoPE on Q and K (in-place in QKV)
  rope<<<10240, 256, 0, stream>>>(QKV);

  // 4) V transpose for PV A-fragments
  vtrans<<<1024, 256, 0, stream>>>(QKV, VT);

  // 5) flash attention (transposed-S)
  attn<<<dim3(32, 32, 2), 256, 0, stream>>>(QKV, VT, amask, Ob);

  // 6) output projection (fp32 out)
  gemm_nt<false><<<dim3(64, 16), 256, 0, stream>>>(Ob, Wob, (void*)out, 1024);
}

// Round 4
// 272.793 us; speedup vs baseline: 1.5396x; 1.4979x over previous
//
#include <hip/hip_runtime.h>

typedef __bf16 bf16x8 __attribute__((ext_vector_type(8)));
typedef __bf16 bf16x4 __attribute__((ext_vector_type(4)));
typedef float f32x4 __attribute__((ext_vector_type(4)));

__device__ __forceinline__ f32x4 mfma16(bf16x8 a, bf16x8 b, f32x4 c) {
  return __builtin_amdgcn_mfma_f32_16x16x32_bf16(a, b, c, 0, 0, 0);
}

__device__ __forceinline__ float fast_exp2(float x) {
  return __builtin_amdgcn_exp2f(x);  // v_exp_f32 (native exp2)
}

// ---------------- fp32 -> bf16 convert ----------------
__global__ __launch_bounds__(256) void f2b(const float* __restrict__ src,
                                           __bf16* __restrict__ dst, int n) {
  int i = (blockIdx.x * 256 + threadIdx.x) * 4;
  if (i < n) {
    float4 v = *(const float4*)(src + i);
    bf16x4 o = { (__bf16)v.x, (__bf16)v.y, (__bf16)v.z, (__bf16)v.w };
    *(bf16x4*)(dst + i) = o;
  }
}

// ---------------- NT GEMM: C[M,N] = A[M,1024] * B[N,1024]^T ----------------
template <bool BF16_OUT>
__global__ __launch_bounds__(256) void gemm_nt(const __bf16* __restrict__ A,
                                               const __bf16* __restrict__ B,
                                               void* __restrict__ Cv, int N) {
  __shared__ __bf16 As[64][32];
  __shared__ __bf16 Bs[64][32];
  const int m0 = blockIdx.x * 64, n0 = blockIdx.y * 64;
  const int tid = threadIdx.x;
  const int wave = tid >> 6, lane = tid & 63, quad = lane >> 4, l16 = lane & 15;
  const int lr = tid >> 2, lc = (tid & 3) * 8;
  f32x4 acc[4] = {};
  const __bf16* Ap = A + (size_t)(m0 + lr) * 1024 + lc;
  const __bf16* Bp = B + (size_t)(n0 + lr) * 1024 + lc;
  for (int k0 = 0; k0 < 1024; k0 += 32) {
    __syncthreads();
    *(uint4*)&As[lr][lc] = *(const uint4*)(Ap + k0);
    *(uint4*)&Bs[lr][lc] = *(const uint4*)(Bp + k0);
    __syncthreads();
    bf16x8 af = *(bf16x8*)&As[wave * 16 + l16][quad * 8];
#pragma unroll
    for (int t = 0; t < 4; t++) {
      bf16x8 bf = *(bf16x8*)&Bs[t * 16 + l16][quad * 8];
      acc[t] = mfma16(af, bf, acc[t]);
    }
  }
#pragma unroll
  for (int t = 0; t < 4; t++) {
#pragma unroll
    for (int r = 0; r < 4; r++) {
      int row = m0 + wave * 16 + quad * 4 + r;
      int col = n0 + t * 16 + l16;
      if constexpr (BF16_OUT)
        ((__bf16*)Cv)[(size_t)row * N + col] = (__bf16)acc[t][r];
      else
        ((float*)Cv)[(size_t)row * N + col] = acc[t][r];
    }
  }
}

// ------- RoPE in-place on QKV [4096,1536]: Q cols 0..1023, K cols 1024..1279
__global__ __launch_bounds__(256) void rope(__bf16* __restrict__ QKV) {
  int idx = blockIdx.x * 256 + threadIdx.x;
  const int nq = 4096 * 32 * 16;
  __bf16* base;
  int m, i;
  if (idx < nq) {
    m = idx >> 9;
    int h = (idx >> 4) & 31;
    i = idx & 15;
    base = QKV + (size_t)m * 1536 + h * 32;
  } else {
    int j = idx - nq;
    m = j >> 7;
    int h = (j >> 4) & 7;
    i = j & 15;
    base = QKV + (size_t)m * 1536 + 1024 + h * 32;
  }
  int s = m & 2047;
  float inv = __expf(-(float)i * 0.5756462732485114f);  // 10000^(-i/16)
  float ang = (float)s * inv;
  float sn, cs;
  __sincosf(ang, &sn, &cs);
  float x0 = (float)base[i];
  float x1 = (float)base[i + 16];
  base[i] = (__bf16)(x0 * cs - x1 * sn);
  base[i + 16] = (__bf16)(x1 * cs + x0 * sn);
}

// ---- V transpose + mask bias: VT[(b*8+hkv)*32+d][s]; maskb[b*2048+s] -------
__global__ __launch_bounds__(256) void vtrans(const __bf16* __restrict__ QKV,
                                              __bf16* __restrict__ VT,
                                              const int* __restrict__ amask,
                                              float* __restrict__ maskb) {
  int idx = blockIdx.x * 256 + threadIdx.x;
  if (idx < 4096) maskb[idx] = amask[idx] ? 0.f : -1.5e9f;
  int s4 = idx & 511;
  int d = (idx >> 9) & 31;
  int hb_ = idx >> 14;
  int s = s4 * 4;
  int b_ = hb_ >> 3, hkv_ = hb_ & 7;
  const __bf16* src = QKV + (size_t)(b_ * 2048 + s) * 1536 + 1280 + hkv_ * 32 + d;
  bf16x4 ov = { src[0], src[1536], src[3072], src[4608] };
  *(bf16x4*)&VT[((size_t)hb_ * 32 + d) * 2048 + s] = ov;
}

// ---------------- Flash attention, LDS-staged K/V, double-buffered ----------
// Block = 64 q rows of one (b,h); 4 waves. S^T = K*Q^T, O^T = V^T*P^T.
__global__ __launch_bounds__(256) void attn(const __bf16* __restrict__ QKV,
                                            const __bf16* __restrict__ VT,
                                            const float* __restrict__ maskb,
                                            __bf16* __restrict__ Ob) {
  __shared__ __bf16 Ks[2][64][40];  // 64 keys x 32 d, pad->80 B rows
  __shared__ __bf16 Vs[2][32][72];  // 32 d x 64 keys, pad->144 B rows
  __shared__ __bf16 Pl[4][16][72];  // per-wave P^T scratch, 144 B rows
  const int tid = threadIdx.x;
  const int wave = tid >> 6, lane = tid & 63;
  const int quad = lane >> 4, l16 = lane & 15;
  const int b = blockIdx.z, h = blockIdx.y, hkv = h >> 2;
  const int x = blockIdx.x;
  const int q0 = x * 64 + wave * 16;
  const int q_row = q0 + l16;
  const float SC2 = 0.25503472f;  // (1/sqrt(32)) * log2(e)

  // Q fragment (B operand): lane holds Q[q0+l16][d=quad*8..+8]
  const __bf16* qptr = QKV + (size_t)(b * 2048 + q0 + l16) * 1536 + h * 32 + quad * 8;
  bf16x8 qf = *(const bf16x8*)qptr;

  // staging source pointers (per thread)
  const int sk_key = tid >> 2, sk_ch = (tid & 3) * 8;
  const int sv_d = tid >> 3, sv_seg = (tid & 7) * 8;
  const __bf16* ksrc = QKV + (size_t)(b * 2048 + sk_key) * 1536 + 1024 + hkv * 32 + sk_ch;
  const __bf16* vsrc = VT + ((size_t)(b * 8 + hkv) * 32 + sv_d) * 2048 + sv_seg;
  const float* mrow = maskb + b * 2048;

  // prologue: stage tile 0 into buffer 0
  {
    uint4 kr = *(const uint4*)ksrc;
    uint4 vr = *(const uint4*)vsrc;
    *(uint4*)&Ks[0][sk_key][sk_ch] = kr;
    *(uint4*)&Vs[0][sv_d][sv_seg] = vr;
  }
  __syncthreads();

  f32x4 o0 = {}, o1 = {};
  float m_r = -INFINITY, l_r = 0.f;
  int buf = 0;

  for (int t = 0; t <= x; t++) {
    const int kv0 = t << 6;
    uint4 kr, vr;
    const bool more = (t < x);
    if (more) {
      kr = *(const uint4*)(ksrc + (size_t)(t + 1) * 64 * 1536);
      vr = *(const uint4*)(vsrc + (size_t)(t + 1) * 64);
    }
    // ---- S^T = K * Q^T ----
    float p[4][4];
    float vmax = -INFINITY;
#pragma unroll
    for (int kt = 0; kt < 4; kt++) {
      bf16x8 kf = *(bf16x8*)&Ks[buf][16 * kt + l16][quad * 8];
      f32x4 z = {};
      f32x4 s = mfma16(kf, qf, z);  // S^T[key=kv0+16kt+4quad+r][q=q_row]
      const int kb = kv0 + 16 * kt + 4 * quad;
      float4 mb = *(const float4*)(mrow + kb);
#pragma unroll
      for (int r = 0; r < 4; r++) {
        float v = fmaf(s[r], SC2, (&mb.x)[r]);  // exp2-domain score + mask bias
        v = (kb + r <= q_row) ? v : -1.5e9f;
        p[kt][r] = v;
        vmax = fmaxf(vmax, v);
      }
    }
    vmax = fmaxf(vmax, __shfl_xor(vmax, 16));
    vmax = fmaxf(vmax, __shfl_xor(vmax, 32));
    float mn = fmaxf(m_r, vmax);
    float alpha = fast_exp2(m_r - mn);
    m_r = mn;
    float rs = 0.f;
#pragma unroll
    for (int kt = 0; kt < 4; kt++)
#pragma unroll
      for (int r = 0; r < 4; r++) {
        p[kt][r] = fast_exp2(p[kt][r] - mn);
        rs += p[kt][r];
      }
    rs += __shfl_xor(rs, 16);
    rs += __shfl_xor(rs, 32);
    l_r = l_r * alpha + rs;
#pragma unroll
    for (int r = 0; r < 4; r++) { o0[r] *= alpha; o1[r] *= alpha; }
    // ---- V frags (issue before P transform to overlap) ----
    bf16x8 vf00 = *(bf16x8*)&Vs[buf][l16][quad * 8];
    bf16x8 vf01 = *(bf16x8*)&Vs[buf][l16][32 + quad * 8];
    bf16x8 vf10 = *(bf16x8*)&Vs[buf][16 + l16][quad * 8];
    bf16x8 vf11 = *(bf16x8*)&Vs[buf][16 + l16][32 + quad * 8];
    // ---- P^T -> LDS -> B-frags ----
#pragma unroll
    for (int kt = 0; kt < 4; kt++) {
      bf16x4 pk = { (__bf16)p[kt][0], (__bf16)p[kt][1],
                    (__bf16)p[kt][2], (__bf16)p[kt][3] };
      *(bf16x4*)&Pl[wave][l16][16 * kt + 4 * quad] = pk;
    }
    asm volatile("s_waitcnt lgkmcnt(0)" ::: "memory");
    bf16x8 pf0 = *(bf16x8*)&Pl[wave][l16][8 * quad];
    bf16x8 pf1 = *(bf16x8*)&Pl[wave][l16][32 + 8 * quad];
    asm volatile("s_waitcnt lgkmcnt(0)" ::: "memory");
    o0 = mfma16(vf00, pf0, o0);
    o0 = mfma16(vf01, pf1, o0);
    o1 = mfma16(vf10, pf0, o1);
    o1 = mfma16(vf11, pf1, o1);
    // ---- stage tile t+1 into the other buffer ----
    if (more) {
      *(uint4*)&Ks[buf ^ 1][sk_key][sk_ch] = kr;
      *(uint4*)&Vs[buf ^ 1][sv_d][sv_seg] = vr;
    }
    __syncthreads();
    buf ^= 1;
  }
  // epilogue: lane holds O[q_row][d = dt*16 + quad*4 + r]
  float inv = 1.0f / l_r;
  size_t row = (size_t)(b * 2048 + q_row);
  bf16x4 w0 = { (__bf16)(o0[0] * inv), (__bf16)(o0[1] * inv),
                (__bf16)(o0[2] * inv), (__bf16)(o0[3] * inv) };
  bf16x4 w1 = { (__bf16)(o1[0] * inv), (__bf16)(o1[1] * inv),
                (__bf16)(o1[2] * inv), (__bf16)(o1[3] * inv) };
  *(bf16x4*)&Ob[row * 1024 + h * 32 + quad * 4] = w0;
  *(bf16x4*)&Ob[row * 1024 + h * 32 + 16 + quad * 4] = w1;
}

extern "C" void kernel_launch(void* const* d_in, const int* in_sizes, int n_in,
                              void* d_out, int out_size, void* d_ws, size_t ws_size,
                              hipStream_t stream) {
  const float* hidden = (const float*)d_in[0];
  const int* amask = (const int*)d_in[1];
  const float* Wq = (const float*)d_in[2];
  const float* Wk = (const float*)d_in[3];
  const float* Wv = (const float*)d_in[4];
  const float* Wo = (const float*)d_in[5];
  float* out = (float*)d_out;

  char* p = (char*)d_ws;
  auto carve = [&](size_t elems) {
    __bf16* r = (__bf16*)p;
    p += ((elems * 2 + 255) / 256) * 256;
    return r;
  };
  __bf16* hb = carve(4096ull * 1024);
  __bf16* Wqkvb = carve(1536ull * 1024);
  __bf16* Wob = carve(1024ull * 1024);
  __bf16* QKV = carve(4096ull * 1536);
  __bf16* VT = carve(4096ull * 256);
  __bf16* Ob = carve(4096ull * 1024);
  float* maskb = (float*)carve(8192);  // 4096 floats

  f2b<<<4096, 256, 0, stream>>>(hidden, hb, 4096 * 1024);
  f2b<<<1024, 256, 0, stream>>>(Wq, Wqkvb, 1024 * 1024);
  f2b<<<256, 256, 0, stream>>>(Wk, Wqkvb + 1024ull * 1024, 256 * 1024);
  f2b<<<256, 256, 0, stream>>>(Wv, Wqkvb + 1280ull * 1024, 256 * 1024);
  f2b<<<1024, 256, 0, stream>>>(Wo, Wob, 1024 * 1024);

  gemm_nt<true><<<dim3(64, 24), 256, 0, stream>>>(hb, Wqkvb, QKV, 1536);

  rope<<<10240, 256, 0, stream>>>(QKV);

  vtrans<<<1024, 256, 0, stream>>>(QKV, VT, amask, maskb);

  attn<<<dim3(32, 32, 2), 256, 0, stream>>>(QKV, VT, maskb, Ob);

  gemm_nt<false><<<dim3(64, 16), 256, 0, stream>>>(Ob, Wob, (void*)out, 1024);
}

// Round 5
// 225.284 us; speedup vs baseline: 1.8642x; 1.2109x over previous
//
#include <hip/hip_runtime.h>

typedef __bf16 bf16x8 __attribute__((ext_vector_type(8)));
typedef __bf16 bf16x4 __attribute__((ext_vector_type(4)));
typedef float f32x4 __attribute__((ext_vector_type(4)));

__device__ __forceinline__ f32x4 mfma16(bf16x8 a, bf16x8 b, f32x4 c) {
  return __builtin_amdgcn_mfma_f32_16x16x32_bf16(a, b, c, 0, 0, 0);
}

__device__ __forceinline__ float fast_exp2(float x) {
  return __builtin_amdgcn_exp2f(x);  // v_exp_f32 (native exp2)
}

// ---------------- fused fp32 -> bf16 convert of all inputs ----------------
// quads: hidden 1048576 | Wq 262144 | Wk 65536 | Wv 65536 | Wo 262144
__global__ __launch_bounds__(256) void prep(const float* __restrict__ hidden,
                                            const float* __restrict__ Wq,
                                            const float* __restrict__ Wk,
                                            const float* __restrict__ Wv,
                                            const float* __restrict__ Wo,
                                            __bf16* __restrict__ hb,
                                            __bf16* __restrict__ Wqkvb,
                                            __bf16* __restrict__ Wob) {
  int q = blockIdx.x * 256 + threadIdx.x;
  const float* src;
  __bf16* dst;
  if (q < 1048576) {
    src = hidden; dst = hb;
  } else if ((q -= 1048576) < 262144) {
    src = Wq; dst = Wqkvb;
  } else if ((q -= 262144) < 65536) {
    src = Wk; dst = Wqkvb + 1048576;
  } else if ((q -= 65536) < 65536) {
    src = Wv; dst = Wqkvb + 1310720;
  } else {
    q -= 65536;
    src = Wo; dst = Wob;
  }
  float4 v = *(const float4*)(src + (size_t)q * 4);
  bf16x4 o = { (__bf16)v.x, (__bf16)v.y, (__bf16)v.z, (__bf16)v.w };
  *(bf16x4*)(dst + (size_t)q * 4) = o;
}

// ---------------- NT GEMM: C[M,N] = A[M,1024] * B[N,1024]^T ----------------
template <bool BF16_OUT>
__global__ __launch_bounds__(256) void gemm_nt(const __bf16* __restrict__ A,
                                               const __bf16* __restrict__ B,
                                               void* __restrict__ Cv, int N) {
  __shared__ __bf16 As[64][32];
  __shared__ __bf16 Bs[64][32];
  const int m0 = blockIdx.x * 64, n0 = blockIdx.y * 64;
  const int tid = threadIdx.x;
  const int wave = tid >> 6, lane = tid & 63, quad = lane >> 4, l16 = lane & 15;
  const int lr = tid >> 2, lc = (tid & 3) * 8;
  f32x4 acc[4] = {};
  const __bf16* Ap = A + (size_t)(m0 + lr) * 1024 + lc;
  const __bf16* Bp = B + (size_t)(n0 + lr) * 1024 + lc;
  for (int k0 = 0; k0 < 1024; k0 += 32) {
    __syncthreads();
    *(uint4*)&As[lr][lc] = *(const uint4*)(Ap + k0);
    *(uint4*)&Bs[lr][lc] = *(const uint4*)(Bp + k0);
    __syncthreads();
    bf16x8 af = *(bf16x8*)&As[wave * 16 + l16][quad * 8];
#pragma unroll
    for (int t = 0; t < 4; t++) {
      bf16x8 bf = *(bf16x8*)&Bs[t * 16 + l16][quad * 8];
      acc[t] = mfma16(af, bf, acc[t]);
    }
  }
#pragma unroll
  for (int t = 0; t < 4; t++) {
#pragma unroll
    for (int r = 0; r < 4; r++) {
      int row = m0 + wave * 16 + quad * 4 + r;
      int col = n0 + t * 16 + l16;
      if constexpr (BF16_OUT)
        ((__bf16*)Cv)[(size_t)row * N + col] = (__bf16)acc[t][r];
      else
        ((float*)Cv)[(size_t)row * N + col] = acc[t][r];
    }
  }
}

// --------- fused RoPE (in-place on QKV) + V transpose + mask bias ----------
// idx < 2097152: Q rope | < 2621440: K rope | else vtrans (+maskb)
__global__ __launch_bounds__(256) void ropevt(__bf16* __restrict__ QKV,
                                              __bf16* __restrict__ VT,
                                              const int* __restrict__ amask,
                                              float* __restrict__ maskb) {
  int idx = blockIdx.x * 256 + threadIdx.x;
  if (idx < 2621440) {
    __bf16* base;
    int m, i;
    if (idx < 2097152) {
      m = idx >> 9;
      int h = (idx >> 4) & 31;
      i = idx & 15;
      base = QKV + (size_t)m * 1536 + h * 32;
    } else {
      int j = idx - 2097152;
      m = j >> 7;
      int h = (j >> 4) & 7;
      i = j & 15;
      base = QKV + (size_t)m * 1536 + 1024 + h * 32;
    }
    int s = m & 2047;
    float inv = __expf(-(float)i * 0.5756462732485114f);  // 10000^(-i/16)
    float ang = (float)s * inv;
    float sn, cs;
    __sincosf(ang, &sn, &cs);
    float x0 = (float)base[i];
    float x1 = (float)base[i + 16];
    base[i] = (__bf16)(x0 * cs - x1 * sn);
    base[i + 16] = (__bf16)(x1 * cs + x0 * sn);
  } else {
    int j = idx - 2621440;
    if (j < 4096) maskb[j] = amask[j] ? -16.0f : -1.5e9f;  // static max folded in
    int s4 = j & 511;
    int d = (j >> 9) & 31;
    int hb_ = j >> 14;
    int s = s4 * 4;
    int b_ = hb_ >> 3, hkv_ = hb_ & 7;
    const __bf16* src = QKV + (size_t)(b_ * 2048 + s) * 1536 + 1280 + hkv_ * 32 + d;
    bf16x4 ov = { src[0], src[1536], src[3072], src[4608] };
    *(bf16x4*)&VT[((size_t)hb_ * 32 + d) * 2048 + s] = ov;
  }
}

// ---------------- Flash attention: 128 q rows/block, 32 q rows/wave ----------
// S^T = K*Q^T (2 q-frags share K-frags); static-max softmax (m=16, no per-tile
// reductions); O^T = V^T*P^T. K/V block-staged in LDS, double-buffered.
__global__ __launch_bounds__(256, 4) void attn(const __bf16* __restrict__ QKV,
                                               const __bf16* __restrict__ VT,
                                               const float* __restrict__ maskb,
                                               __bf16* __restrict__ Ob) {
  __shared__ __bf16 Ks[2][64][40];
  __shared__ __bf16 Vs[2][32][72];
  __shared__ __bf16 Pl[4][16][72];
  const int tid = threadIdx.x;
  const int wave = tid >> 6, lane = tid & 63;
  const int quad = lane >> 4, l16 = lane & 15;
  const int b = blockIdx.z, h = blockIdx.y, hkv = h >> 2;
  const int x = blockIdx.x;
  const int qw = x * 128 + wave * 32;  // wave's first q row
  const int q_row0 = qw + l16, q_row1 = qw + 16 + l16;
  const float SC2 = 0.25503472f;  // (1/sqrt(32)) * log2(e)

  // Q fragments (B operand): lane holds Q[q][d=quad*8..+8]
  const __bf16* qbase = QKV + (size_t)(b * 2048 + qw + l16) * 1536 + h * 32 + quad * 8;
  bf16x8 qf0 = *(const bf16x8*)qbase;
  bf16x8 qf1 = *(const bf16x8*)(qbase + 16 * 1536);

  // staging source pointers (per thread)
  const int sk_key = tid >> 2, sk_ch = (tid & 3) * 8;
  const int sv_d = tid >> 3, sv_seg = (tid & 7) * 8;
  const __bf16* ksrc = QKV + (size_t)(b * 2048 + sk_key) * 1536 + 1024 + hkv * 32 + sk_ch;
  const __bf16* vsrc = VT + ((size_t)(b * 8 + hkv) * 32 + sv_d) * 2048 + sv_seg;
  const float* mrow = maskb + b * 2048;

  {  // prologue: stage tile 0 into buffer 0
    uint4 kr = *(const uint4*)ksrc;
    uint4 vr = *(const uint4*)vsrc;
    *(uint4*)&Ks[0][sk_key][sk_ch] = kr;
    *(uint4*)&Vs[0][sv_d][sv_seg] = vr;
  }
  __syncthreads();

  f32x4 o00 = {}, o01 = {}, o10 = {}, o11 = {};  // o[qt][dt]
  float rs0 = 0.f, rs1 = 0.f;                    // per-lane partial row sums
  int buf = 0;
  const int ntiles = 2 * x + 2;

  for (int t = 0; t < ntiles; t++) {
    const int kv0 = t << 6;
    const bool more = (t + 1 < ntiles);
    uint4 kr, vr;
    if (more) {
      kr = *(const uint4*)(ksrc + (size_t)(t + 1) * 64 * 1536);
      vr = *(const uint4*)(vsrc + (size_t)(t + 1) * 64);
    }
    if (kv0 <= qw + 31) {  // wave-uniform: any key visible to this wave?
      // ---- S^T = K * Q^T (K-frags shared across the 2 q-tiles) ----
      bf16x8 kf[4];
#pragma unroll
      for (int kt = 0; kt < 4; kt++)
        kf[kt] = *(bf16x8*)&Ks[buf][16 * kt + l16][quad * 8];
      f32x4 s0[4], s1[4];
#pragma unroll
      for (int kt = 0; kt < 4; kt++) {
        f32x4 z = {};
        s0[kt] = mfma16(kf[kt], qf0, z);
        s1[kt] = mfma16(kf[kt], qf1, z);
      }
      // ---- static-max softmax (no cross-lane work in-loop) ----
      float p0[4][4], p1[4][4];
#pragma unroll
      for (int kt = 0; kt < 4; kt++) {
        const int kb = kv0 + 16 * kt + 4 * quad;
        float4 mb = *(const float4*)(mrow + kb);
#pragma unroll
        for (int r = 0; r < 4; r++) {
          const int key = kb + r;
          float e0 = fast_exp2(fmaf(s0[kt][r], SC2, (&mb.x)[r]));
          float e1 = fast_exp2(fmaf(s1[kt][r], SC2, (&mb.x)[r]));
          p0[kt][r] = (key <= q_row0) ? e0 : 0.f;
          p1[kt][r] = (key <= q_row1) ? e1 : 0.f;
          rs0 += p0[kt][r];
          rs1 += p1[kt][r];
        }
      }
      // ---- V fragments (A operand), shared across q-tiles ----
      bf16x8 vf00 = *(bf16x8*)&Vs[buf][l16][quad * 8];
      bf16x8 vf01 = *(bf16x8*)&Vs[buf][l16][32 + quad * 8];
      bf16x8 vf10 = *(bf16x8*)&Vs[buf][16 + l16][quad * 8];
      bf16x8 vf11 = *(bf16x8*)&Vs[buf][16 + l16][32 + quad * 8];
      // ---- qt0: P^T -> LDS -> B-frags -> PV ----
#pragma unroll
      for (int kt = 0; kt < 4; kt++) {
        bf16x4 pk = { (__bf16)p0[kt][0], (__bf16)p0[kt][1],
                      (__bf16)p0[kt][2], (__bf16)p0[kt][3] };
        *(bf16x4*)&Pl[wave][l16][16 * kt + 4 * quad] = pk;
      }
      asm volatile("s_waitcnt lgkmcnt(0)" ::: "memory");
      {
        bf16x8 pf0 = *(bf16x8*)&Pl[wave][l16][8 * quad];
        bf16x8 pf1 = *(bf16x8*)&Pl[wave][l16][32 + 8 * quad];
        asm volatile("s_waitcnt lgkmcnt(0)" ::: "memory");
        o00 = mfma16(vf00, pf0, o00);
        o00 = mfma16(vf01, pf1, o00);
        o01 = mfma16(vf10, pf0, o01);
        o01 = mfma16(vf11, pf1, o01);
      }
      // ---- qt1 ----
#pragma unroll
      for (int kt = 0; kt < 4; kt++) {
        bf16x4 pk = { (__bf16)p1[kt][0], (__bf16)p1[kt][1],
                      (__bf16)p1[kt][2], (__bf16)p1[kt][3] };
        *(bf16x4*)&Pl[wave][l16][16 * kt + 4 * quad] = pk;
      }
      asm volatile("s_waitcnt lgkmcnt(0)" ::: "memory");
      {
        bf16x8 pf0 = *(bf16x8*)&Pl[wave][l16][8 * quad];
        bf16x8 pf1 = *(bf16x8*)&Pl[wave][l16][32 + 8 * quad];
        asm volatile("s_waitcnt lgkmcnt(0)" ::: "memory");
        o10 = mfma16(vf00, pf0, o10);
        o10 = mfma16(vf01, pf1, o10);
        o11 = mfma16(vf10, pf0, o11);
        o11 = mfma16(vf11, pf1, o11);
      }
    }
    // ---- stage tile t+1 into the other buffer ----
    if (more) {
      *(uint4*)&Ks[buf ^ 1][sk_key][sk_ch] = kr;
      *(uint4*)&Vs[buf ^ 1][sv_d][sv_seg] = vr;
    }
    __syncthreads();
    buf ^= 1;
  }
  // ---- epilogue: one reduction per q-tile, normalize, store ----
  rs0 += __shfl_xor(rs0, 16);
  rs0 += __shfl_xor(rs0, 32);
  rs1 += __shfl_xor(rs1, 16);
  rs1 += __shfl_xor(rs1, 32);
  float inv0 = 1.0f / rs0, inv1 = 1.0f / rs1;
  size_t row0 = (size_t)(b * 2048 + q_row0);
  size_t row1 = (size_t)(b * 2048 + q_row1);
  bf16x4 w00 = { (__bf16)(o00[0] * inv0), (__bf16)(o00[1] * inv0),
                 (__bf16)(o00[2] * inv0), (__bf16)(o00[3] * inv0) };
  bf16x4 w01 = { (__bf16)(o01[0] * inv0), (__bf16)(o01[1] * inv0),
                 (__bf16)(o01[2] * inv0), (__bf16)(o01[3] * inv0) };
  bf16x4 w10 = { (__bf16)(o10[0] * inv1), (__bf16)(o10[1] * inv1),
                 (__bf16)(o10[2] * inv1), (__bf16)(o10[3] * inv1) };
  bf16x4 w11 = { (__bf16)(o11[0] * inv1), (__bf16)(o11[1] * inv1),
                 (__bf16)(o11[2] * inv1), (__bf16)(o11[3] * inv1) };
  *(bf16x4*)&Ob[row0 * 1024 + h * 32 + quad * 4] = w00;
  *(bf16x4*)&Ob[row0 * 1024 + h * 32 + 16 + quad * 4] = w01;
  *(bf16x4*)&Ob[row1 * 1024 + h * 32 + quad * 4] = w10;
  *(bf16x4*)&Ob[row1 * 1024 + h * 32 + 16 + quad * 4] = w11;
}

extern "C" void kernel_launch(void* const* d_in, const int* in_sizes, int n_in,
                              void* d_out, int out_size, void* d_ws, size_t ws_size,
                              hipStream_t stream) {
  const float* hidden = (const float*)d_in[0];
  const int* amask = (const int*)d_in[1];
  const float* Wq = (const float*)d_in[2];
  const float* Wk = (const float*)d_in[3];
  const float* Wv = (const float*)d_in[4];
  const float* Wo = (const float*)d_in[5];
  float* out = (float*)d_out;

  char* p = (char*)d_ws;
  auto carve = [&](size_t elems) {
    __bf16* r = (__bf16*)p;
    p += ((elems * 2 + 255) / 256) * 256;
    return r;
  };
  __bf16* hb = carve(4096ull * 1024);
  __bf16* Wqkvb = carve(1536ull * 1024);
  __bf16* Wob = carve(1024ull * 1024);
  __bf16* QKV = carve(4096ull * 1536);
  __bf16* VT = carve(4096ull * 256);
  __bf16* Ob = carve(4096ull * 1024);
  float* maskb = (float*)carve(8192);  // 4096 floats

  prep<<<6656, 256, 0, stream>>>(hidden, Wq, Wk, Wv, Wo, hb, Wqkvb, Wob);

  gemm_nt<true><<<dim3(64, 24), 256, 0, stream>>>(hb, Wqkvb, QKV, 1536);

  ropevt<<<11264, 256, 0, stream>>>(QKV, VT, amask, maskb);

  attn<<<dim3(16, 32, 2), 256, 0, stream>>>(QKV, VT, maskb, Ob);

  gemm_nt<false><<<dim3(64, 16), 256, 0, stream>>>(Ob, Wob, (void*)out, 1024);
}

// Round 6
// 194.963 us; speedup vs baseline: 2.1542x; 1.1555x over previous
//
#include <hip/hip_runtime.h>

typedef __bf16 bf16x8 __attribute__((ext_vector_type(8)));
typedef __bf16 bf16x4 __attribute__((ext_vector_type(4)));
typedef float f32x4 __attribute__((ext_vector_type(4)));

__device__ __forceinline__ f32x4 mfma16(bf16x8 a, bf16x8 b, f32x4 c) {
  return __builtin_amdgcn_mfma_f32_16x16x32_bf16(a, b, c, 0, 0, 0);
}

__device__ __forceinline__ float fast_exp2(float x) {
  return __builtin_amdgcn_exp2f(x);  // v_exp_f32 (native exp2)
}

// ---------------- fused fp32 -> bf16 convert of all inputs ----------------
__global__ __launch_bounds__(256) void prep(const float* __restrict__ hidden,
                                            const float* __restrict__ Wq,
                                            const float* __restrict__ Wk,
                                            const float* __restrict__ Wv,
                                            const float* __restrict__ Wo,
                                            __bf16* __restrict__ hb,
                                            __bf16* __restrict__ Wqkvb,
                                            __bf16* __restrict__ Wob) {
  int q = blockIdx.x * 256 + threadIdx.x;
  const float* src;
  __bf16* dst;
  if (q < 1048576) {
    src = hidden; dst = hb;
  } else if ((q -= 1048576) < 262144) {
    src = Wq; dst = Wqkvb;
  } else if ((q -= 262144) < 65536) {
    src = Wk; dst = Wqkvb + 1048576;
  } else if ((q -= 65536) < 65536) {
    src = Wv; dst = Wqkvb + 1310720;
  } else {
    q -= 65536;
    src = Wo; dst = Wob;
  }
  float4 v = *(const float4*)(src + (size_t)q * 4);
  bf16x4 o = { (__bf16)v.x, (__bf16)v.y, (__bf16)v.z, (__bf16)v.w };
  *(bf16x4*)(dst + (size_t)q * 4) = o;
}

// ------ NT GEMM, 128x128 tile, dbuf LDS: C[M,N] = A[M,1024]*B[N,1024]^T -----
// 4 waves in 2x2; each wave a 64x64 quadrant = 4x4 MFMAs of 16x16x32.
template <bool BF16_OUT>
__global__ __launch_bounds__(256) void gemm_nt(const __bf16* __restrict__ A,
                                               const __bf16* __restrict__ B,
                                               void* __restrict__ Cv, int N) {
  __shared__ __bf16 As[2][128][32];
  __shared__ __bf16 Bs[2][128][32];
  const int m0 = blockIdx.x * 128, n0 = blockIdx.y * 128;
  const int tid = threadIdx.x;
  const int wave = tid >> 6, lane = tid & 63, quad = lane >> 4, l16 = lane & 15;
  const int wr = wave >> 1, wc = wave & 1;
  const int sr = tid >> 1, sc = (tid & 1) * 16;  // staging: row, 16-elem half
  f32x4 acc[4][4] = {};
  const __bf16* Ap = A + (size_t)(m0 + sr) * 1024 + sc;
  const __bf16* Bp = B + (size_t)(n0 + sr) * 1024 + sc;
  {  // prologue: tile 0 -> buf 0
    uint4 a0 = *(const uint4*)Ap, a1 = *(const uint4*)(Ap + 8);
    uint4 b0 = *(const uint4*)Bp, b1 = *(const uint4*)(Bp + 8);
    *(uint4*)&As[0][sr][sc] = a0;
    *(uint4*)&As[0][sr][sc + 8] = a1;
    *(uint4*)&Bs[0][sr][sc] = b0;
    *(uint4*)&Bs[0][sr][sc + 8] = b1;
  }
  __syncthreads();
  int buf = 0;
  for (int k0 = 0; k0 < 1024; k0 += 32) {
    const bool more = (k0 + 32) < 1024;
    uint4 na0, na1, nb0, nb1;
    if (more) {
      na0 = *(const uint4*)(Ap + k0 + 32);
      na1 = *(const uint4*)(Ap + k0 + 40);
      nb0 = *(const uint4*)(Bp + k0 + 32);
      nb1 = *(const uint4*)(Bp + k0 + 40);
    }
    bf16x8 af[4], bfr[4];
#pragma unroll
    for (int i = 0; i < 4; i++)
      af[i] = *(bf16x8*)&As[buf][64 * wr + 16 * i + l16][quad * 8];
#pragma unroll
    for (int j = 0; j < 4; j++)
      bfr[j] = *(bf16x8*)&Bs[buf][64 * wc + 16 * j + l16][quad * 8];
#pragma unroll
    for (int i = 0; i < 4; i++)
#pragma unroll
      for (int j = 0; j < 4; j++) acc[i][j] = mfma16(af[i], bfr[j], acc[i][j]);
    if (more) {
      *(uint4*)&As[buf ^ 1][sr][sc] = na0;
      *(uint4*)&As[buf ^ 1][sr][sc + 8] = na1;
      *(uint4*)&Bs[buf ^ 1][sr][sc] = nb0;
      *(uint4*)&Bs[buf ^ 1][sr][sc + 8] = nb1;
    }
    __syncthreads();
    buf ^= 1;
  }
#pragma unroll
  for (int i = 0; i < 4; i++)
#pragma unroll
    for (int j = 0; j < 4; j++)
#pragma unroll
      for (int r = 0; r < 4; r++) {
        int row = m0 + 64 * wr + 16 * i + quad * 4 + r;
        int col = n0 + 64 * wc + 16 * j + l16;
        if constexpr (BF16_OUT)
          ((__bf16*)Cv)[(size_t)row * N + col] = (__bf16)acc[i][j][r];
        else
          ((float*)Cv)[(size_t)row * N + col] = acc[i][j][r];
      }
}

// --------- fused RoPE (in-place on QKV) + V transpose + mask bias ----------
__global__ __launch_bounds__(256) void ropevt(__bf16* __restrict__ QKV,
                                              __bf16* __restrict__ VT,
                                              const int* __restrict__ amask,
                                              float* __restrict__ maskb) {
  int idx = blockIdx.x * 256 + threadIdx.x;
  if (idx < 2621440) {
    __bf16* base;
    int m, i;
    if (idx < 2097152) {
      m = idx >> 9;
      int h = (idx >> 4) & 31;
      i = idx & 15;
      base = QKV + (size_t)m * 1536 + h * 32;
    } else {
      int j = idx - 2097152;
      m = j >> 7;
      int h = (j >> 4) & 7;
      i = j & 15;
      base = QKV + (size_t)m * 1536 + 1024 + h * 32;
    }
    int s = m & 2047;
    float inv = __expf(-(float)i * 0.5756462732485114f);  // 10000^(-i/16)
    float ang = (float)s * inv;
    float sn, cs;
    __sincosf(ang, &sn, &cs);
    float x0 = (float)base[i];
    float x1 = (float)base[i + 16];
    base[i] = (__bf16)(x0 * cs - x1 * sn);
    base[i + 16] = (__bf16)(x1 * cs + x0 * sn);
  } else {
    int j = idx - 2621440;
    if (j < 4096) maskb[j] = amask[j] ? -16.0f : -1.5e9f;  // static max folded in
    int s4 = j & 511;
    int d = (j >> 9) & 31;
    int hb_ = j >> 14;
    int s = s4 * 4;
    int b_ = hb_ >> 3, hkv_ = hb_ & 7;
    const __bf16* src = QKV + (size_t)(b_ * 2048 + s) * 1536 + 1280 + hkv_ * 32 + d;
    bf16x4 ov = { src[0], src[1536], src[3072], src[4608] };
    *(bf16x4*)&VT[((size_t)hb_ * 32 + d) * 2048 + s] = ov;
  }
}

// ---------------- Flash attention: paired q-strips for uniform work ----------
// Block xp handles q-strips {xp, 15-xp} (128 rows each) sequentially ->
// every block does exactly 34 tile-iters. Wave = 32 q rows. Static-max
// softmax; full tiles skip causal cndmask; single Pl wait round per tile.
__global__ __launch_bounds__(256, 4) void attn(const __bf16* __restrict__ QKV,
                                               const __bf16* __restrict__ VT,
                                               const float* __restrict__ maskb,
                                               __bf16* __restrict__ Ob) {
  __shared__ __bf16 Ks[2][64][40];
  __shared__ __bf16 Vs[2][32][72];
  __shared__ __bf16 Pl[4][2][16][72];
  const int tid = threadIdx.x;
  const int wave = tid >> 6, lane = tid & 63;
  const int quad = lane >> 4, l16 = lane & 15;
  const int b = blockIdx.z, h = blockIdx.y, hkv = h >> 2;
  const int xp = blockIdx.x;  // 0..7
  const float SC2 = 0.25503472f;  // (1/sqrt(32)) * log2(e)

  const int sk_key = tid >> 2, sk_ch = (tid & 3) * 8;
  const int sv_d = tid >> 3, sv_seg = (tid & 7) * 8;
  const __bf16* ksrc = QKV + (size_t)(b * 2048 + sk_key) * 1536 + 1024 + hkv * 32 + sk_ch;
  const __bf16* vsrc = VT + ((size_t)(b * 8 + hkv) * 32 + sv_d) * 2048 + sv_seg;
  const float* mrow = maskb + b * 2048;

  for (int sp = 0; sp < 2; sp++) {
    const int strip = sp ? 15 - xp : xp;
    const int qw = strip * 128 + wave * 32;
    const int q_row0 = qw + l16, q_row1 = qw + 16 + l16;
    const __bf16* qbase = QKV + (size_t)(b * 2048 + qw + l16) * 1536 + h * 32 + quad * 8;
    bf16x8 qf0 = *(const bf16x8*)qbase;
    bf16x8 qf1 = *(const bf16x8*)(qbase + 16 * 1536);

    {  // stage tile 0 into buffer 0 (prev strip's loop fully barriered)
      uint4 kr = *(const uint4*)ksrc;
      uint4 vr = *(const uint4*)vsrc;
      *(uint4*)&Ks[0][sk_key][sk_ch] = kr;
      *(uint4*)&Vs[0][sv_d][sv_seg] = vr;
    }
    __syncthreads();

    f32x4 o00 = {}, o01 = {}, o10 = {}, o11 = {};
    float rs0 = 0.f, rs1 = 0.f;
    int buf = 0;
    const int ntiles = 2 * strip + 2;

    for (int t = 0; t < ntiles; t++) {
      const int kv0 = t << 6;
      const bool more = (t + 1 < ntiles);
      uint4 kr, vr;
      if (more) {
        kr = *(const uint4*)(ksrc + (size_t)(t + 1) * 64 * 1536);
        vr = *(const uint4*)(vsrc + (size_t)(t + 1) * 64);
      }
      if (kv0 <= qw + 31) {  // wave-uniform: any visible key?
        bf16x8 kf[4];
#pragma unroll
        for (int kt = 0; kt < 4; kt++)
          kf[kt] = *(bf16x8*)&Ks[buf][16 * kt + l16][quad * 8];
        f32x4 s0[4], s1[4];
#pragma unroll
        for (int kt = 0; kt < 4; kt++) {
          f32x4 z = {};
          s0[kt] = mfma16(kf[kt], qf0, z);
          s1[kt] = mfma16(kf[kt], qf1, z);
        }
        float p0[4][4], p1[4][4];
        if (kv0 + 63 <= qw) {  // full tile: no causal test
#pragma unroll
          for (int kt = 0; kt < 4; kt++) {
            const int kb = kv0 + 16 * kt + 4 * quad;
            float4 mb = *(const float4*)(mrow + kb);
#pragma unroll
            for (int r = 0; r < 4; r++) {
              float e0 = fast_exp2(fmaf(s0[kt][r], SC2, (&mb.x)[r]));
              float e1 = fast_exp2(fmaf(s1[kt][r], SC2, (&mb.x)[r]));
              p0[kt][r] = e0;
              p1[kt][r] = e1;
              rs0 += e0;
              rs1 += e1;
            }
          }
        } else {  // diagonal tile
#pragma unroll
          for (int kt = 0; kt < 4; kt++) {
            const int kb = kv0 + 16 * kt + 4 * quad;
            float4 mb = *(const float4*)(mrow + kb);
#pragma unroll
            for (int r = 0; r < 4; r++) {
              const int key = kb + r;
              float e0 = fast_exp2(fmaf(s0[kt][r], SC2, (&mb.x)[r]));
              float e1 = fast_exp2(fmaf(s1[kt][r], SC2, (&mb.x)[r]));
              p0[kt][r] = (key <= q_row0) ? e0 : 0.f;
              p1[kt][r] = (key <= q_row1) ? e1 : 0.f;
              rs0 += p0[kt][r];
              rs1 += p1[kt][r];
            }
          }
        }
        // V fragments (A operand), shared across q-tiles
        bf16x8 vf00 = *(bf16x8*)&Vs[buf][l16][quad * 8];
        bf16x8 vf01 = *(bf16x8*)&Vs[buf][l16][32 + quad * 8];
        bf16x8 vf10 = *(bf16x8*)&Vs[buf][16 + l16][quad * 8];
        bf16x8 vf11 = *(bf16x8*)&Vs[buf][16 + l16][32 + quad * 8];
        // both q-tiles' P -> LDS, one wait round
#pragma unroll
        for (int kt = 0; kt < 4; kt++) {
          bf16x4 pa = { (__bf16)p0[kt][0], (__bf16)p0[kt][1],
                        (__bf16)p0[kt][2], (__bf16)p0[kt][3] };
          bf16x4 pb = { (__bf16)p1[kt][0], (__bf16)p1[kt][1],
                        (__bf16)p1[kt][2], (__bf16)p1[kt][3] };
          *(bf16x4*)&Pl[wave][0][l16][16 * kt + 4 * quad] = pa;
          *(bf16x4*)&Pl[wave][1][l16][16 * kt + 4 * quad] = pb;
        }
        asm volatile("s_waitcnt lgkmcnt(0)" ::: "memory");
        bf16x8 pf00 = *(bf16x8*)&Pl[wave][0][l16][8 * quad];
        bf16x8 pf01 = *(bf16x8*)&Pl[wave][0][l16][32 + 8 * quad];
        bf16x8 pf10 = *(bf16x8*)&Pl[wave][1][l16][8 * quad];
        bf16x8 pf11 = *(bf16x8*)&Pl[wave][1][l16][32 + 8 * quad];
        asm volatile("s_waitcnt lgkmcnt(0)" ::: "memory");
        o00 = mfma16(vf00, pf00, o00);
        o00 = mfma16(vf01, pf01, o00);
        o01 = mfma16(vf10, pf00, o01);
        o01 = mfma16(vf11, pf01, o01);
        o10 = mfma16(vf00, pf10, o10);
        o10 = mfma16(vf01, pf11, o10);
        o11 = mfma16(vf10, pf10, o11);
        o11 = mfma16(vf11, pf11, o11);
      }
      if (more) {
        *(uint4*)&Ks[buf ^ 1][sk_key][sk_ch] = kr;
        *(uint4*)&Vs[buf ^ 1][sv_d][sv_seg] = vr;
      }
      __syncthreads();
      buf ^= 1;
    }
    // epilogue for this strip
    rs0 += __shfl_xor(rs0, 16);
    rs0 += __shfl_xor(rs0, 32);
    rs1 += __shfl_xor(rs1, 16);
    rs1 += __shfl_xor(rs1, 32);
    float inv0 = 1.0f / rs0, inv1 = 1.0f / rs1;
    size_t row0 = (size_t)(b * 2048 + q_row0);
    size_t row1 = (size_t)(b * 2048 + q_row1);
    bf16x4 w00 = { (__bf16)(o00[0] * inv0), (__bf16)(o00[1] * inv0),
                   (__bf16)(o00[2] * inv0), (__bf16)(o00[3] * inv0) };
    bf16x4 w01 = { (__bf16)(o01[0] * inv0), (__bf16)(o01[1] * inv0),
                   (__bf16)(o01[2] * inv0), (__bf16)(o01[3] * inv0) };
    bf16x4 w10 = { (__bf16)(o10[0] * inv1), (__bf16)(o10[1] * inv1),
                   (__bf16)(o10[2] * inv1), (__bf16)(o10[3] * inv1) };
    bf16x4 w11 = { (__bf16)(o11[0] * inv1), (__bf16)(o11[1] * inv1),
                   (__bf16)(o11[2] * inv1), (__bf16)(o11[3] * inv1) };
    *(bf16x4*)&Ob[row0 * 1024 + h * 32 + quad * 4] = w00;
    *(bf16x4*)&Ob[row0 * 1024 + h * 32 + 16 + quad * 4] = w01;
    *(bf16x4*)&Ob[row1 * 1024 + h * 32 + quad * 4] = w10;
    *(bf16x4*)&Ob[row1 * 1024 + h * 32 + 16 + quad * 4] = w11;
  }
}

extern "C" void kernel_launch(void* const* d_in, const int* in_sizes, int n_in,
                              void* d_out, int out_size, void* d_ws, size_t ws_size,
                              hipStream_t stream) {
  const float* hidden = (const float*)d_in[0];
  const int* amask = (const int*)d_in[1];
  const float* Wq = (const float*)d_in[2];
  const float* Wk = (const float*)d_in[3];
  const float* Wv = (const float*)d_in[4];
  const float* Wo = (const float*)d_in[5];
  float* out = (float*)d_out;

  char* p = (char*)d_ws;
  auto carve = [&](size_t elems) {
    __bf16* r = (__bf16*)p;
    p += ((elems * 2 + 255) / 256) * 256;
    return r;
  };
  __bf16* hb = carve(4096ull * 1024);
  __bf16* Wqkvb = carve(1536ull * 1024);
  __bf16* Wob = carve(1024ull * 1024);
  __bf16* QKV = carve(4096ull * 1536);
  __bf16* VT = carve(4096ull * 256);
  __bf16* Ob = carve(4096ull * 1024);
  float* maskb = (float*)carve(8192);  // 4096 floats

  prep<<<6656, 256, 0, stream>>>(hidden, Wq, Wk, Wv, Wo, hb, Wqkvb, Wob);

  gemm_nt<true><<<dim3(32, 12), 256, 0, stream>>>(hb, Wqkvb, QKV, 1536);

  ropevt<<<11264, 256, 0, stream>>>(QKV, VT, amask, maskb);

  attn<<<dim3(8, 32, 2), 256, 0, stream>>>(QKV, VT, maskb, Ob);

  gemm_nt<false><<<dim3(32, 8), 256, 0, stream>>>(Ob, Wob, (void*)out, 1024);
}